// Round 1
// baseline (177.741 us; speedup 1.0000x reference)
//
#include <hip/hip_runtime.h>
#include <stdint.h>

typedef float v4f __attribute__((ext_vector_type(4)));
typedef int v8i __attribute__((ext_vector_type(8)));

#define FP8_DENOM 358.4f  // FP8_MAX(448) * SCALE_MARGIN(0.8)

// ---------- helpers ----------

__device__ __forceinline__ unsigned pack4_fp8(float a, float b, float c, float d) {
  // v_cvt_pk_fp8_f32: RNE, saturating (values <=358.4 by construction)
  int v = 0;
  v = __builtin_amdgcn_cvt_pk_fp8_f32(a, b, v, false);  // bytes 0,1
  v = __builtin_amdgcn_cvt_pk_fp8_f32(c, d, v, true);   // bytes 2,3
  return (unsigned)v;
}

__device__ __forceinline__ void gload_lds16(const void* g, void* l) {
  // 16B-wide async global->LDS. LDS dest must be wave-uniform base + lane*16.
  __builtin_amdgcn_global_load_lds(
      (const __attribute__((address_space(1))) uint32_t*)(uintptr_t)g,
      (__attribute__((address_space(3))) uint32_t*)(uint32_t)(uintptr_t)l,
      16, 0, 0);
}

// ---------- stage 1: per-block amax -> single atomicMax ----------
// blocks 0..1023 cover x (4096 float4 each), blocks 1024..1279 cover w.
// amax[0]=amax_x bits, amax[1]=amax_w bits (uint-bit compare == float compare
// for non-negative floats). amax[] zeroed by hipMemsetAsync before launch.

__global__ void __launch_bounds__(256) amax_part(const float4* __restrict__ x,
                                                 const float4* __restrict__ w,
                                                 unsigned* __restrict__ amax) {
  const int b = blockIdx.x, t = threadIdx.x;
  const float4* p = (b < 1024) ? x : w;
  const long base = (long)((b < 1024) ? b : (b - 1024)) * 4096;
  float m0 = 0.f, m1 = 0.f, m2 = 0.f, m3 = 0.f;
#pragma unroll
  for (int j = 0; j < 4; ++j) {
    float4 v0 = p[base + (j * 4 + 0) * 256 + t];
    float4 v1 = p[base + (j * 4 + 1) * 256 + t];
    float4 v2 = p[base + (j * 4 + 2) * 256 + t];
    float4 v3 = p[base + (j * 4 + 3) * 256 + t];
    m0 = fmaxf(m0, fmaxf(fmaxf(fabsf(v0.x), fabsf(v0.y)), fmaxf(fabsf(v0.z), fabsf(v0.w))));
    m1 = fmaxf(m1, fmaxf(fmaxf(fabsf(v1.x), fabsf(v1.y)), fmaxf(fabsf(v1.z), fabsf(v1.w))));
    m2 = fmaxf(m2, fmaxf(fmaxf(fabsf(v2.x), fabsf(v2.y)), fmaxf(fabsf(v2.z), fabsf(v2.w))));
    m3 = fmaxf(m3, fmaxf(fmaxf(fabsf(v3.x), fabsf(v3.y)), fmaxf(fabsf(v3.z), fabsf(v3.w))));
  }
  float m = fmaxf(fmaxf(m0, m1), fmaxf(m2, m3));
#pragma unroll
  for (int off = 32; off > 0; off >>= 1)
    m = fmaxf(m, __shfl_down(m, off, 64));
  __shared__ float red[4];
  const int lane = t & 63, wvid = t >> 6;
  if (lane == 0) red[wvid] = m;
  __syncthreads();
  if (t == 0)
    atomicMax(amax + ((b < 1024) ? 0 : 1),
              __float_as_uint(fmaxf(fmaxf(red[0], red[1]), fmaxf(red[2], red[3]))));
}

// ---------- stage 2: fused quantize x and w -> fp8 e4m3fn codes ----------
// Coalesced: lane i reads float4 i (1KB contiguous per wave-instr), writes one
// packed unsigned (256B contiguous per wave-instr). Scales computed inline from
// amax bits with the exact float expressions used previously (bit-identical).
// blocks 0..4095 cover x (1024 float4 each), 4096..5119 cover w.

__global__ void __launch_bounds__(256) quant2_kernel(
    const float4* __restrict__ x, unsigned* __restrict__ xq,
    const float4* __restrict__ w, unsigned* __restrict__ wq,
    const unsigned* __restrict__ amax) {
  const int t = threadIdx.x;
  const int isw = ((int)blockIdx.x >= 4096) ? 1 : 0;
  const float ax = __uint_as_float(amax[0]);
  const float aw = __uint_as_float(amax[1]);
  const float s = (isw ? fmaxf(ax, aw) : ax) / FP8_DENOM;  // shared amax history max for w
  const float rs = 1.0f / s;
  const float4* in = isw ? w : x;
  unsigned* outq = isw ? wq : xq;
  const long base = (long)(isw ? ((int)blockIdx.x - 4096) : (int)blockIdx.x) * 1024;
#pragma unroll
  for (int j = 0; j < 4; ++j) {
    float4 v = in[base + j * 256 + t];
    outq[base + j * 256 + t] = pack4_fp8(v.x * rs, v.y * rs, v.z * rs, v.w * rs);
  }
}

// ---------- MX-scaled fp8 GEMM, 256x256 tile, double-buffered LDS ----------
// M=8192 N=2048 K=2048. 256x256x128 tile, 8 waves (2x4 -> 128x64 each),
// 16x16x128 mfma_scale with unit e8m0 scales. Previous 128x128 version:
// MfmaUtil 26.6% -- compute window per K-iter (~275 SIMD-cy) < staging latency,
// so the barrier drain exposed memory latency every iteration, and the
// 1024-block grid ran 2 rounds over 512 resident slots. This version doubles
// the MFMA work per drain window (2 waves/SIMD x 32 MFMA ~ 550 cy), halves
// LDS-write staging traffic per FLOP, and the 256-block grid is exactly
// 1 block/CU (128KB LDS). Fragment math and XOR-chunk swizzle carried over
// unchanged from the verified kernel.

__global__ void __launch_bounds__(512, 2) gemm_mx(
    const uint8_t* __restrict__ Aq, const uint8_t* __restrict__ Bq,
    const float* __restrict__ bias, float* __restrict__ out,
    const unsigned* __restrict__ amax) {
  constexpr int K = 2048, N = 2048, BK = 128, ITERS = K / BK;
  __shared__ alignas(16) uint8_t sA[2][256 * BK];  // 2 x 32 KB
  __shared__ alignas(16) uint8_t sB[2][256 * BK];  // 2 x 32 KB

  const int tid = threadIdx.x;
  const int lane = tid & 63;
  const int wid = tid >> 6;               // 0..7
  const int wy = wid >> 2, wx = wid & 3;  // 2x4 waves -> 128x64 per wave
  const long tileM = (long)blockIdx.y * 256;
  const long tileN = (long)blockIdx.x * 256;

  v4f acc[8][4];
#pragma unroll
  for (int i = 0; i < 8; ++i)
#pragma unroll
    for (int j = 0; j < 4; ++j) acc[i][j] = (v4f)(0.f);

  // staging: thread t -> row srow = t>>3 (+ s*64), phys chunk t&7,
  // source logical chunk = (t&7) ^ (srow&7)  (row&7 invariant across s: 64%8==0)
  const int srow = tid >> 3;  // 0..63
  const int schunk = (tid & 7) ^ (srow & 7);
  const uint8_t* gA = Aq + (tileM + srow) * K + schunk * 16;
  const uint8_t* gB = Bq + (tileN + srow) * K + schunk * 16;

  const int q = lane >> 4;     // k-block: lane holds k = q*32 .. q*32+31
  const int mrow = lane & 15;  // row within 16x16 tile
  // (row & 7) == (mrow & 7) for every fragment row (all row bases are mult of 8),
  // so the swizzled chunk offsets are loop-invariant scalars; frag i/j adds i*16*BK.
  const int sw = mrow & 7;
  const int aoff0 = (wy * 128 + mrow) * BK + 16 * ((2 * q) ^ sw);
  const int aoff1 = (wy * 128 + mrow) * BK + 16 * ((2 * q + 1) ^ sw);
  const int boff0 = (wx * 64 + mrow) * BK + 16 * ((2 * q) ^ sw);
  const int boff1 = (wx * 64 + mrow) * BK + 16 * ((2 * q + 1) ^ sw);

  auto stage = [&](int buf, int k0) {
#pragma unroll
    for (int s = 0; s < 4; ++s) {
      gload_lds16(gA + (long)s * 64 * K + k0, &sA[buf][s * 8192 + tid * 16]);
      gload_lds16(gB + (long)s * 64 * K + k0, &sB[buf][s * 8192 + tid * 16]);
    }
  };

  stage(0, 0);
  for (int it = 0; it < ITERS; ++it) {
    __syncthreads();  // drains staging(it) — overlapped with prev iter's MFMAs
    if (it + 1 < ITERS) stage((it + 1) & 1, (it + 1) * BK);  // async prefetch

    const uint8_t* bufA = sA[it & 1];
    const uint8_t* bufB = sB[it & 1];
    union Frag { v8i v; uint4 h[2]; };
    Frag b[4];
#pragma unroll
    for (int j = 0; j < 4; ++j) {
      b[j].h[0] = *(const uint4*)(bufB + boff0 + j * 16 * BK);
      b[j].h[1] = *(const uint4*)(bufB + boff1 + j * 16 * BK);
    }
    __builtin_amdgcn_s_setprio(1);
#pragma unroll
    for (int i = 0; i < 8; ++i) {
      Frag a;
      a.h[0] = *(const uint4*)(bufA + aoff0 + i * 16 * BK);
      a.h[1] = *(const uint4*)(bufA + aoff1 + i * 16 * BK);
#pragma unroll
      for (int j = 0; j < 4; ++j)
        acc[i][j] = __builtin_amdgcn_mfma_scale_f32_16x16x128_f8f6f4(
            a.v, b[j].v, acc[i][j], /*cbsz=fp8*/ 0, /*blgp=fp8*/ 0,
            /*opsel_a*/ 0, 0x7F7F7F7F, /*opsel_b*/ 0, 0x7F7F7F7F);  // e8m0 127 = x1.0
    }
    __builtin_amdgcn_s_setprio(0);
  }

  // epilogue: C/D layout col=lane&15, row=(lane>>4)*4+reg (shape-determined).
  // scale computed inline, bit-identical to previous sx*sw.
  const float ax = __uint_as_float(amax[0]);
  const float aw = __uint_as_float(amax[1]);
  const float scale = (ax / FP8_DENOM) * (fmaxf(ax, aw) / FP8_DENOM);
#pragma unroll
  for (int j = 0; j < 4; ++j) {
    const long col = tileN + wx * 64 + j * 16 + mrow;
    const float bv = bias[col];
#pragma unroll
    for (int i = 0; i < 8; ++i) {
      const long row = tileM + wy * 128 + i * 16 + q * 4;
#pragma unroll
      for (int r = 0; r < 4; ++r)
        out[(row + r) * N + col] = acc[i][j][r] * scale + bv;
    }
  }
}

// ---------- launch ----------

extern "C" void kernel_launch(void* const* d_in, const int* in_sizes, int n_in,
                              void* d_out, int out_size, void* d_ws, size_t ws_size,
                              hipStream_t stream) {
  const float* x = (const float*)d_in[0];     // [4,2048,2048] -> [8192,2048]
  const float* w = (const float*)d_in[1];     // [2048,2048]
  const float* bias = (const float*)d_in[2];  // [2048]
  float* out = (float*)d_out;                 // [8192,2048] fp32

  const int M = 8192, N = 2048, K = 2048;
  const long nx = (long)M * K;

  // ws layout: [0,8): amax bits (x,w); [8192, 8192+nx): xq codes; then wq codes.
  unsigned* amax = (unsigned*)d_ws;
  uint8_t* xq = (uint8_t*)d_ws + 8192;
  uint8_t* wq = xq + nx;

  hipMemsetAsync(amax, 0, 8, stream);  // graph-capturable
  amax_part<<<1280, 256, 0, stream>>>((const float4*)x, (const float4*)w, amax);
  quant2_kernel<<<5120, 256, 0, stream>>>((const float4*)x, (unsigned*)xq,
                                          (const float4*)w, (unsigned*)wq, amax);
  gemm_mx<<<dim3(N / 256, M / 256), 512, 0, stream>>>(xq, wq, bias, out, amax);
}